// Round 8
// baseline (7386.548 us; speedup 1.0000x reference)
//
#include <hip/hip_runtime.h>
#include <hip/hip_fp16.h>

// CascadedAttention: B=32, T=1024, D=1024, O=256. All I/O f32.
// ws (33.55 MB): E[b][t][o]=exp(2*(in@Ua+Ba2)) bf16; IC[b][t][o]=in@Co bf16.
// UoHp staged in d_out (f32), read at step t before the step's publish,
// overwritten by pred only after the step-t exchange completes.
// Scan: 256 blocks x 512 thr; b=blk&31, g=blk>>5.
// R14 = R10 base with the exchange replaced by a SINGLE-RTT tagged protocol:
//  - publish: tid<256 store (t<<16)|f16(P) to g_P[par][b][g][tid] (plain
//    relaxed agent stores); tid0 early-publishes tagged m,S after stats.
//  - NO flags, NO release drain, NO post-flag batch load: each merge thread
//    polls its own 8 tagged P words with plain agent loads (the poll load IS
//    the data load); lanes<16 poll the 16 tagged mS words, shfl broadcast.
//  - barriers 10 -> 7/step (S7 drain, S8, S8b deleted).
// Correctness: tag travels inside the word (per-word atomic store) -> no
// fence needed; uoh load is sampled at S1's vmcnt(0) drain, long before our
// tags are visible, so the out-row ordering argument is unchanged; skew<=1
// step -> parity-2 buffers safe; tag t never matches t-2 or init 0xFFFF.
// All blocks merge identical f16 words -> bitwise-identical preds.
// Retained: phase-C oq-stagger (R8 PMC: LDS conflicts 8.05e8 -> 0), R10
// stats structure, f32->f16 pack only at the exchange (absmax 0.03125
// proven across R7-R13).
// (R15 = R14 resubmission: round 7 bench was a GPUAcquisitionTimeout, the
//  kernel itself was never measured.)

typedef unsigned int uint32;
typedef unsigned short u16;

#define NTH 512

__device__ __forceinline__ float b2f(u16 u) { return __uint_as_float(((uint32)u) << 16); }
__device__ __forceinline__ u16 f2b(float f) {
    uint32 u = __float_as_uint(f);
    uint32 r = u + 0x7fffu + ((u >> 16) & 1u);
    return (u16)(r >> 16);
}
__device__ __forceinline__ float lo_bf(uint32 d) { return __uint_as_float(d << 16); }
__device__ __forceinline__ float hi_bf(uint32 d) { return __uint_as_float(d & 0xffff0000u); }
__device__ __forceinline__ float tanh_fast(float x) {
    float e = __expf(x + x);
    return 1.0f - 2.0f * __builtin_amdgcn_rcpf(e + 1.0f);
}
__device__ __forceinline__ uint32 packh(float f, int t) {
    return (((uint32)t) << 16) | (uint32)__half_as_ushort(__float2half(f));
}
__device__ __forceinline__ float unpackh(uint32 w) {
    return __half2float(__ushort_as_half((unsigned short)(w & 0xFFFFu)));
}

__device__ __forceinline__ uint32 coh_ld(const uint32* p) {
    return __hip_atomic_load(p, __ATOMIC_RELAXED, __HIP_MEMORY_SCOPE_AGENT);
}
__device__ __forceinline__ void coh_st(uint32* p, uint32 v) {
    __hip_atomic_store(p, v, __ATOMIC_RELAXED, __HIP_MEMORY_SCOPE_AGENT);
}

#define OFF_E  ((size_t)0)
#define OFF_IC ((size_t)16777216)
#define WS_NEEDED ((size_t)33554432)

// exchange: per (parity,b,g): tagged P words [0..255] (stride 264);
// g_mSt: per (parity,b): 16 tagged words, [2g]=m_g, [2g+1]=S_g
__device__ uint32 g_P[2][32][8][264];
__device__ uint32 g_mSt[2][32][16];
__device__ float g_embWo[256];

#define NP_WORDS (2 * 32 * 8 * 264)     // 135168
#define NMS_WORDS (2 * 32 * 16)         // 1024
// (135168 + 1024) / 256 = 532 blocks

__global__ __launch_bounds__(256) void init_k() {
    int i = blockIdx.x * 256 + threadIdx.x;
    if (i < NP_WORDS) ((uint32*)g_P)[i] = 0xFFFF0000u;
    else ((uint32*)g_mSt)[i - NP_WORDS] = 0xFFFF0000u;
}

__global__ void setup_embWo(const float* __restrict__ emb, const float* __restrict__ Wo) {
    int o = threadIdx.x;
    float a = 0.f;
    for (int j = 0; j < 256; j++) a = fmaf(emb[o * 256 + j], Wo[j], a);
    g_embWo[o] = a;
}

// ---------------- K1: fused precompute GEMM (f32 in) ----------------
__global__ __launch_bounds__(256) void gemm_pre(
    const float* __restrict__ in, const float* __restrict__ Ua,
    const float* __restrict__ Uo, const float* __restrict__ Co,
    const float* __restrict__ Ba2, const float* __restrict__ Bo2,
    const float* __restrict__ Bo3, const float* __restrict__ Bo4,
    u16* __restrict__ E, float* __restrict__ outStage, u16* __restrict__ ic) {
    __shared__ __align__(16) float smA[32][132];
    __shared__ __align__(16) float smB[32][128];

    int tid = threadIdx.x;
    int rt = blockIdx.x, ct = blockIdx.y;
    int mat = ct >> 1;
    int o0 = (ct & 1) * 128;
    const float* W = (mat == 0) ? Ua : (mat == 1 ? Uo : Co);
    int r0 = rt * 128;
    int b = r0 >> 10, t0 = r0 & 1023;
    int tr = tid >> 4, tc = tid & 15;

    float acc[8][8];
#pragma unroll
    for (int i = 0; i < 8; i++)
#pragma unroll
        for (int j = 0; j < 8; j++) acc[i][j] = 0.f;

    for (int kc = 0; kc < 1024; kc += 32) {
#pragma unroll
        for (int l = 0; l < 4; l++) {
            int s = tid + l * 256;
            int i = s >> 3, c = s & 7;
            float4 v = *(const float4*)(in + (size_t)(r0 + i) * 1024 + kc + c * 4);
            smA[c * 4 + 0][i] = v.x;
            smA[c * 4 + 1][i] = v.y;
            smA[c * 4 + 2][i] = v.z;
            smA[c * 4 + 3][i] = v.w;
        }
#pragma unroll
        for (int l = 0; l < 4; l++) {
            int s = tid + l * 256;
            int dd = s >> 5, c = s & 31;
            *(float4*)&smB[dd][c * 4] = *(const float4*)(W + (size_t)(kc + dd) * 256 + o0 + c * 4);
        }
        __syncthreads();
#pragma unroll 4
        for (int j = 0; j < 32; j++) {
            float a0[8], b0[8];
            *(float4*)&a0[0] = *(const float4*)&smA[j][tr * 8];
            *(float4*)&a0[4] = *(const float4*)&smA[j][tr * 8 + 4];
            *(float4*)&b0[0] = *(const float4*)&smB[j][tc * 8];
            *(float4*)&b0[4] = *(const float4*)&smB[j][tc * 8 + 4];
#pragma unroll
            for (int rr = 0; rr < 8; rr++)
#pragma unroll
                for (int cc = 0; cc < 8; cc++) acc[rr][cc] = fmaf(a0[rr], b0[cc], acc[rr][cc]);
        }
        __syncthreads();
    }

    if (mat == 0) {
#pragma unroll
        for (int rr = 0; rr < 8; rr++) {
            int t = t0 + tr * 8 + rr;
#pragma unroll
            for (int cc = 0; cc < 8; cc++) {
                int o = o0 + tc * 8 + cc;
                float v = __expf(2.f * (acc[rr][cc] + Ba2[t * 256 + o]));
                E[((((size_t)b << 10) + t) << 8) + o] = f2b(v);   // [b][t][o]
            }
        }
    } else if (mat == 1) {
#pragma unroll
        for (int rr = 0; rr < 8; rr++) {
            int t = t0 + tr * 8 + rr;
            int t1 = (t + 1) & 1023;
#pragma unroll
            for (int cc = 0; cc < 8; cc++) {
                int o = o0 + tc * 8 + cc;
                outStage[(((size_t)b << 10) + t1) * 256 + o] = acc[rr][cc] + Bo2[o] + Bo3[o] + Bo4[o];
            }
        }
    } else {
#pragma unroll
        for (int rr = 0; rr < 8; rr++) {
            int t = t0 + tr * 8 + rr;
#pragma unroll
            for (int cc = 0; cc < 8; cc++)
                ic[(((size_t)b << 10) + t) * 256 + o0 + tc * 8 + cc] = f2b(acc[rr][cc]);
        }
    }
}

// ---------------- K2: scan, 8 blocks/b x 512 thr, tagged exchange/step ------
__global__ __launch_bounds__(NTH) void seq8(
    const float* __restrict__ Wa, const float* __restrict__ Va,
    const float* __restrict__ Ba1, const float* __restrict__ Ba3,
    const u16* __restrict__ E, const u16* __restrict__ IC,
    float* __restrict__ out) {
    __shared__ uint32 smWa2[128 * 256];     // 128 KB bf16-packed Wa
    __shared__ __align__(16) float smScratch[2048];
    __shared__ float smPred[256], smQ[256], smF[256], smVa[256], smBa1[256];
    __shared__ float smS[128], smEe[128], smBa3[128];
    __shared__ float smT[16];

    int tid = threadIdx.x;
    int b = blockIdx.x & 31, g = blockIdx.x >> 5;
    int lane = tid & 63, w = tid >> 6;
    int t0 = g << 7;

    if (tid < 256) {
        smVa[tid] = Va[tid]; smBa1[tid] = Ba1[tid];
        smPred[tid] = 0.f; smQ[tid] = 0.f;
    }
    if (tid < 128) smBa3[tid] = Ba3[t0 + tid];
    for (int idx = tid; idx < 32768; idx += NTH) {
        int j2 = idx >> 8, o = idx & 255;
        uint32 u0 = (uint32)f2b(Wa[(size_t)(2 * j2) * 256 + o]);
        uint32 u1 = (uint32)f2b(Wa[(size_t)(2 * j2 + 1) * 256 + o]);
        smWa2[idx] = u0 | (u1 << 16);
    }
    __syncthreads();

    float sv = (tid < 256) ? smVa[tid] : 0.f;
#pragma unroll
    for (int off = 32; off; off >>= 1) sv += __shfl_xor(sv, off, 64);
    if (lane == 0) smT[w] = sv;
    __syncthreads();
    float sumVa = smT[0] + smT[1] + smT[2] + smT[3];
    float myEmb = (tid < 256) ? g_embWo[tid] : 0.f;
    __syncthreads();

    const u16* Eb = E + ((size_t)b << 18);
    const u16* ICb = IC + ((size_t)b << 18);
    float* outb = out + ((size_t)b << 18);
    long bud = 1000000000L;   // hang guard (bounded: wrong result, not timeout)

    for (int t = 0; t < 1024; t++) {
        uint32* bufP = &g_P[t & 1][b][g][0];
        uint32* msb  = &g_mSt[t & 1][b][0];
        // UoHp row read — sampled at S1's vmcnt(0) drain, i.e. strictly before
        // our step-t tags become visible -> out-row ordering safe.
        float uoh = (tid < 256) ? outb[((size_t)t << 8) + tid] : 0.f;

        // ---- phase A partials (tid<256) + WaS GEMV (all 512) ----
        float pv = 0.f;
        if (tid < 256) {
            pv = smPred[tid];
            float m = pv;
#pragma unroll
            for (int off = 32; off; off >>= 1) m = fmaxf(m, __shfl_xor(m, off, 64));
            if (lane == 0) smT[w] = m;
        }
        {
            int o = tid & 255, h = tid >> 8;
            const uint32* wp = &smWa2[(h << 6) * 256 + o];
            const float* qp = &smQ[h << 7];
            float a = 0.f;
#pragma unroll 8
            for (int j2 = 0; j2 < 64; j2++) {
                float2 q2 = *(const float2*)&qp[j2 * 2];
                uint32 p = wp[j2 << 8];
                a = fmaf(lo_bf(p), q2.x, a);
                a = fmaf(hi_bf(p), q2.y, a);
            }
            smScratch[tid] = a;
        }
        __syncthreads();   // S1
        if (tid < 256) {
            float M = fmaxf(fmaxf(smT[0], smT[1]), fmaxf(smT[2], smT[3]));
            float e = __expf(pv - M);
            float s1 = e, s2 = e * myEmb;
#pragma unroll
            for (int off = 32; off; off >>= 1) {
                s1 += __shfl_xor(s1, off, 64);
                s2 += __shfl_xor(s2, off, 64);
            }
            if (lane == 0) { smT[4 + w] = s1; smT[8 + w] = s2; }
            smF[tid] = __expf(2.f * (smBa1[tid] + smScratch[tid] + smScratch[256 + tid]));
        }
        __syncthreads();   // S2
        float p_val = (smT[8] + smT[9] + smT[10] + smT[11]) *
                      __builtin_amdgcn_rcpf(smT[4] + smT[5] + smT[6] + smT[7]);

        // ---- phase C: scores for own 128-t' slice, 4 thr/row ----
        // k staggered by oq (R8 PMC: LDS conflicts 8.05e8 -> 0)
        {
            int tl = tid >> 2, oq = tid & 3;
            const uint4* row = (const uint4*)(Eb + (((size_t)(t0 + tl)) << 8) + (oq << 6));
            float acc = 0.f;
#pragma unroll
            for (int k = 0; k < 8; k++) {
                int kk = (k + oq) & 7;
                uint4 ev = row[kk];
                int ob = (oq << 6) + (kk << 3);
                float4 fA = *(const float4*)&smF[ob];
                float4 fB = *(const float4*)&smF[ob + 4];
                float4 vA = *(const float4*)&smVa[ob];
                float4 vB = *(const float4*)&smVa[ob + 4];
                acc = fmaf(vA.x, __builtin_amdgcn_rcpf(fmaf(lo_bf(ev.x), fA.x, 1.f)), acc);
                acc = fmaf(vA.y, __builtin_amdgcn_rcpf(fmaf(hi_bf(ev.x), fA.y, 1.f)), acc);
                acc = fmaf(vA.z, __builtin_amdgcn_rcpf(fmaf(lo_bf(ev.y), fA.z, 1.f)), acc);
                acc = fmaf(vA.w, __builtin_amdgcn_rcpf(fmaf(hi_bf(ev.y), fA.w, 1.f)), acc);
                acc = fmaf(vB.x, __builtin_amdgcn_rcpf(fmaf(lo_bf(ev.z), fB.x, 1.f)), acc);
                acc = fmaf(vB.y, __builtin_amdgcn_rcpf(fmaf(hi_bf(ev.z), fB.y, 1.f)), acc);
                acc = fmaf(vB.z, __builtin_amdgcn_rcpf(fmaf(lo_bf(ev.w), fB.z, 1.f)), acc);
                acc = fmaf(vB.w, __builtin_amdgcn_rcpf(fmaf(hi_bf(ev.w), fB.w, 1.f)), acc);
            }
            acc += __shfl_xor(acc, 1, 64);
            acc += __shfl_xor(acc, 2, 64);
            if (oq == 0) smS[tl] = sumVa - 2.f * acc + smBa3[tl];
        }
        __syncthreads();   // S3
        // ---- local softmax stats over 128 scores (R10 structure) ----
        float m_g = 0.f, S_g = 0.f;
        if (tid < 128) {
            float s = smS[tid];
            float mm = s;
#pragma unroll
            for (int off = 32; off; off >>= 1) mm = fmaxf(mm, __shfl_xor(mm, off, 64));
            if (lane == 0) smT[w] = mm;
        }
        __syncthreads();   // S4
        if (tid < 128) {
            m_g = fmaxf(smT[0], smT[1]);
            float e = __expf(smS[tid] - m_g);
            smEe[tid] = e;
            float ls = e;
#pragma unroll
            for (int off = 32; off; off >>= 1) ls += __shfl_xor(ls, off, 64);
            if (lane == 0) smT[2 + w] = ls;
        }
        __syncthreads();   // S5
        m_g = fmaxf(smT[0], smT[1]);
        S_g = smT[2] + smT[3];
        // early tagged publish of m,S: travels while we stage P
        if (tid == 0) {
            coh_st(&msb[2 * g], packh(m_g, t));
            coh_st(&msb[2 * g + 1], packh(S_g, t));
        }

        // ---- P_g partial: e-weighted IC rows of own slice ----
        {
            int rg = tid >> 6, oc = tid & 63, o4 = oc << 2;
            const u16* icp = ICb + (((size_t)t0) << 8) + o4;
            float4 a4 = {0.f, 0.f, 0.f, 0.f};
#pragma unroll 4
            for (int r = 0; r < 16; r++) {
                int row = (rg << 4) + r;
                float e = smEe[row];
                uint2 iv = *(const uint2*)(icp + ((size_t)row << 8));
                a4.x = fmaf(e, lo_bf(iv.x), a4.x);
                a4.y = fmaf(e, hi_bf(iv.x), a4.y);
                a4.z = fmaf(e, lo_bf(iv.y), a4.z);
                a4.w = fmaf(e, hi_bf(iv.y), a4.w);
            }
            *(float4*)&smScratch[rg * 256 + o4] = a4;
        }
        __syncthreads();   // S6
        // ---- publish P (tagged, plain stores) then IMMEDIATELY poll ----
        if (tid < 256) {
            float Pmine = 0.f;
#pragma unroll
            for (int rg = 0; rg < 8; rg++) Pmine += smScratch[rg * 256 + tid];
            coh_st(&bufP[tid], packh(Pmine, t));

            // ---- single-RTT poll: my 8 tagged P words + 16 mS (lanes<16) ----
            const uint32* pb = &g_P[t & 1][b][0][0];
            uint32 tt = (uint32)t;
            uint32 w0 = 0xFFFF0000u, w1 = 0xFFFF0000u, w2 = 0xFFFF0000u,
                   w3 = 0xFFFF0000u, w4 = 0xFFFF0000u, w5 = 0xFFFF0000u,
                   w6 = 0xFFFF0000u, w7 = 0xFFFF0000u;
            uint32 msv = (lane < 16) ? 0xFFFF0000u : (tt << 16);
            while (bud > 0) {
                if ((w0 >> 16) != tt) w0 = coh_ld(pb + 0 * 264 + tid);
                if ((w1 >> 16) != tt) w1 = coh_ld(pb + 1 * 264 + tid);
                if ((w2 >> 16) != tt) w2 = coh_ld(pb + 2 * 264 + tid);
                if ((w3 >> 16) != tt) w3 = coh_ld(pb + 3 * 264 + tid);
                if ((w4 >> 16) != tt) w4 = coh_ld(pb + 4 * 264 + tid);
                if ((w5 >> 16) != tt) w5 = coh_ld(pb + 5 * 264 + tid);
                if ((w6 >> 16) != tt) w6 = coh_ld(pb + 6 * 264 + tid);
                if ((w7 >> 16) != tt) w7 = coh_ld(pb + 7 * 264 + tid);
                if ((msv >> 16) != tt) msv = coh_ld(msb + (lane & 15));
                bool done = ((w0 >> 16) == tt) && ((w1 >> 16) == tt) &&
                            ((w2 >> 16) == tt) && ((w3 >> 16) == tt) &&
                            ((w4 >> 16) == tt) && ((w5 >> 16) == tt) &&
                            ((w6 >> 16) == tt) && ((w7 >> 16) == tt) &&
                            ((msv >> 16) == tt);
                if (__all(done)) break;
                bud--;
            }
            // ---- merge (all values from identical f16 words) ----
            float mg0 = unpackh(__shfl(msv, 0, 64)),  sg0 = unpackh(__shfl(msv, 1, 64));
            float mg1 = unpackh(__shfl(msv, 2, 64)),  sg1 = unpackh(__shfl(msv, 3, 64));
            float mg2 = unpackh(__shfl(msv, 4, 64)),  sg2 = unpackh(__shfl(msv, 5, 64));
            float mg3 = unpackh(__shfl(msv, 6, 64)),  sg3 = unpackh(__shfl(msv, 7, 64));
            float mg4 = unpackh(__shfl(msv, 8, 64)),  sg4 = unpackh(__shfl(msv, 9, 64));
            float mg5 = unpackh(__shfl(msv, 10, 64)), sg5 = unpackh(__shfl(msv, 11, 64));
            float mg6 = unpackh(__shfl(msv, 12, 64)), sg6 = unpackh(__shfl(msv, 13, 64));
            float mg7 = unpackh(__shfl(msv, 14, 64)), sg7 = unpackh(__shfl(msv, 15, 64));
            float M = fmaxf(fmaxf(fmaxf(mg0, mg1), fmaxf(mg2, mg3)),
                            fmaxf(fmaxf(mg4, mg5), fmaxf(mg6, mg7)));
            float e0 = __expf(mg0 - M), e1 = __expf(mg1 - M);
            float e2 = __expf(mg2 - M), e3 = __expf(mg3 - M);
            float e4 = __expf(mg4 - M), e5 = __expf(mg5 - M);
            float e6 = __expf(mg6 - M), e7 = __expf(mg7 - M);
            float L = e0 * sg0 + e1 * sg1 + e2 * sg2 + e3 * sg3 +
                      e4 * sg4 + e5 * sg5 + e6 * sg6 + e7 * sg7;
            float Pt = e0 * unpackh(w0) + e1 * unpackh(w1) +
                       e2 * unpackh(w2) + e3 * unpackh(w3) +
                       e4 * unpackh(w4) + e5 * unpackh(w5) +
                       e6 * unpackh(w6) + e7 * unpackh(w7);
            float pr = p_val + uoh + Pt * __builtin_amdgcn_rcpf(L);
            if ((tid >> 5) == g) outb[((size_t)t << 8) + tid] = pr;
            smPred[tid] = pr;
            smQ[tid] = tanh_fast(pr);
        }
        __syncthreads();   // S9
    }
}

// ---------------- fallback (ws too small): diagnostic zero-fill ----------------
__global__ void zero_k(uint32* out, int n) {
    int i = blockIdx.x * 1024 + threadIdx.x;
    if (i < n) out[i] = 0;
}

extern "C" void kernel_launch(void* const* d_in, const int* in_sizes, int n_in,
                              void* d_out, int out_size, void* d_ws, size_t ws_size,
                              hipStream_t stream) {
    const float* in = (const float*)d_in[0];
    const float* Wa = (const float*)d_in[1];
    const float* Ua = (const float*)d_in[2];
    const float* Va = (const float*)d_in[3];
    const float* Ba1 = (const float*)d_in[4];
    const float* Ba2 = (const float*)d_in[5];
    const float* Ba3 = (const float*)d_in[6];
    const float* Wo = (const float*)d_in[7];
    const float* Uo = (const float*)d_in[8];
    const float* Co = (const float*)d_in[9];
    const float* Bo2 = (const float*)d_in[10];
    const float* Bo3 = (const float*)d_in[11];
    const float* Bo4 = (const float*)d_in[12];
    const float* emb = (const float*)d_in[13];
    float* out = (float*)d_out;
    char* ws = (char*)d_ws;

    if (ws_size < WS_NEEDED) {
        zero_k<<<(out_size + 1023) / 1024, 1024, 0, stream>>>((uint32*)out, out_size);
        return;
    }

    u16* E = (u16*)(ws + OFF_E);
    u16* icp = (u16*)(ws + OFF_IC);

    init_k<<<532, 256, 0, stream>>>();
    setup_embWo<<<1, 256, 0, stream>>>(emb, Wo);
    gemm_pre<<<dim3(256, 6), 256, 0, stream>>>(in, Ua, Uo, Co, Ba2, Bo2, Bo3, Bo4, E, out, icp);
    seq8<<<256, NTH, 0, stream>>>(Wa, Va, Ba1, Ba3, E, icp, out);
}

// Round 9
// 6676.692 us; speedup vs baseline: 1.1063x; 1.1063x over previous
//
#include <hip/hip_runtime.h>
#include <hip/hip_fp16.h>

// CascadedAttention: B=32, T=1024, D=1024, O=256. All I/O f32.
// ws (33.55 MB): E[b][t][o]=exp(2*(in@Ua+Ba2)) bf16; IC[b][t][o]=in@Co bf16.
// UoHp staged in d_out (f32), read at step t before the step's publish,
// overwritten by pred only after the step-t exchange completes.
// Scan: 256 blocks x 512 thr; b=blk&31, g=blk>>5.
// R16 = R10 base (flag + bulk-load exchange, BEST measured: 6530 us) with a
// FIXED-M0 softmax replacing the per-group-max machinery:
//  - scores are bounded: |Sum_o Va_o*tanh(.)| <= Sum|Va|; M0 = Sum|Va| +
//    max(Ba3) + 1 precomputed once in setup -> e = exp(s-M0) in (0,1], all
//    f32-normal; softmax is shift-invariant so the math is unchanged.
//  - e + per-wave S_g partial sums computed INSIDE phase C (the xor-butterfly
//    already gives every quad lane the row score) -> stats barriers S4,S5
//    and the m_g exchange word deleted.
//  - merge is pure sums: pred = p_val + uoh + (Sum P_g)/(Sum S_g) — no exp,
//    no max. S_g rides the P buffer at word 256; merge loads it lane<8+shfl.
//  - barriers 10 -> 7 per step (S1,S2,S3,S6,S7,S8,S9).
// Exchange protocol byte-identical to R10 (proven best vs R9/R13/R14):
// f32 publish -> S7 barrier (vmcnt drain = release) -> flag=t -> poll 7
// foreign flags (atomicAdd+0) -> S8 -> ONE pipelined bulk load -> merge.
// Retained: phase-C oq-stagger (R8 PMC: LDS conflicts 8.05e8 -> 0).

typedef unsigned int uint32;
typedef unsigned short u16;

#define NTH 512

__device__ __forceinline__ float b2f(u16 u) { return __uint_as_float(((uint32)u) << 16); }
__device__ __forceinline__ u16 f2b(float f) {
    uint32 u = __float_as_uint(f);
    uint32 r = u + 0x7fffu + ((u >> 16) & 1u);
    return (u16)(r >> 16);
}
__device__ __forceinline__ float lo_bf(uint32 d) { return __uint_as_float(d << 16); }
__device__ __forceinline__ float hi_bf(uint32 d) { return __uint_as_float(d & 0xffff0000u); }
__device__ __forceinline__ float tanh_fast(float x) {
    float e = __expf(x + x);
    return 1.0f - 2.0f * __builtin_amdgcn_rcpf(e + 1.0f);
}

__device__ __forceinline__ uint32 coh_ld(const uint32* p) {
    return __hip_atomic_load(p, __ATOMIC_RELAXED, __HIP_MEMORY_SCOPE_AGENT);
}
__device__ __forceinline__ void coh_st(uint32* p, uint32 v) {
    __hip_atomic_store(p, v, __ATOMIC_RELAXED, __HIP_MEMORY_SCOPE_AGENT);
}

#define OFF_E  ((size_t)0)
#define OFF_IC ((size_t)16777216)
#define WS_NEEDED ((size_t)33554432)

// exchange: per (parity,b,g): P f32-bits [0..255], S_g at 256 (264 stride)
__device__ uint32 g_Pf[2][32][8][264];
__device__ uint32 g_flag[2][32][8];     // flag word = t when group g's data ready
__device__ float g_embWo[256];
__device__ float g_M0;                  // fixed softmax shift (upper bound on scores)

__global__ __launch_bounds__(512) void init_flags() {
    ((uint32*)g_flag)[threadIdx.x] = 0xFFFFFFFFu;    // 2*32*8 = 512 words
}

__global__ void setup_misc(const float* __restrict__ emb, const float* __restrict__ Wo,
                           const float* __restrict__ Va, const float* __restrict__ Ba3) {
    int o = threadIdx.x;
    float a = 0.f;
    for (int j = 0; j < 256; j++) a = fmaf(emb[o * 256 + j], Wo[j], a);
    g_embWo[o] = a;
    if (o == 0) {
        float sa = 0.f;
        for (int j = 0; j < 256; j++) sa += fabsf(Va[j]);
        float mb = Ba3[0];
        for (int j = 1; j < 1024; j++) mb = fmaxf(mb, Ba3[j]);
        g_M0 = sa + mb + 1.0f;          // strict upper bound on any score
    }
}

// ---------------- K1: fused precompute GEMM (f32 in) ----------------
__global__ __launch_bounds__(256) void gemm_pre(
    const float* __restrict__ in, const float* __restrict__ Ua,
    const float* __restrict__ Uo, const float* __restrict__ Co,
    const float* __restrict__ Ba2, const float* __restrict__ Bo2,
    const float* __restrict__ Bo3, const float* __restrict__ Bo4,
    u16* __restrict__ E, float* __restrict__ outStage, u16* __restrict__ ic) {
    __shared__ __align__(16) float smA[32][132];
    __shared__ __align__(16) float smB[32][128];

    int tid = threadIdx.x;
    int rt = blockIdx.x, ct = blockIdx.y;
    int mat = ct >> 1;
    int o0 = (ct & 1) * 128;
    const float* W = (mat == 0) ? Ua : (mat == 1 ? Uo : Co);
    int r0 = rt * 128;
    int b = r0 >> 10, t0 = r0 & 1023;
    int tr = tid >> 4, tc = tid & 15;

    float acc[8][8];
#pragma unroll
    for (int i = 0; i < 8; i++)
#pragma unroll
        for (int j = 0; j < 8; j++) acc[i][j] = 0.f;

    for (int kc = 0; kc < 1024; kc += 32) {
#pragma unroll
        for (int l = 0; l < 4; l++) {
            int s = tid + l * 256;
            int i = s >> 3, c = s & 7;
            float4 v = *(const float4*)(in + (size_t)(r0 + i) * 1024 + kc + c * 4);
            smA[c * 4 + 0][i] = v.x;
            smA[c * 4 + 1][i] = v.y;
            smA[c * 4 + 2][i] = v.z;
            smA[c * 4 + 3][i] = v.w;
        }
#pragma unroll
        for (int l = 0; l < 4; l++) {
            int s = tid + l * 256;
            int dd = s >> 5, c = s & 31;
            *(float4*)&smB[dd][c * 4] = *(const float4*)(W + (size_t)(kc + dd) * 256 + o0 + c * 4);
        }
        __syncthreads();
#pragma unroll 4
        for (int j = 0; j < 32; j++) {
            float a0[8], b0[8];
            *(float4*)&a0[0] = *(const float4*)&smA[j][tr * 8];
            *(float4*)&a0[4] = *(const float4*)&smA[j][tr * 8 + 4];
            *(float4*)&b0[0] = *(const float4*)&smB[j][tc * 8];
            *(float4*)&b0[4] = *(const float4*)&smB[j][tc * 8 + 4];
#pragma unroll
            for (int rr = 0; rr < 8; rr++)
#pragma unroll
                for (int cc = 0; cc < 8; cc++) acc[rr][cc] = fmaf(a0[rr], b0[cc], acc[rr][cc]);
        }
        __syncthreads();
    }

    if (mat == 0) {
#pragma unroll
        for (int rr = 0; rr < 8; rr++) {
            int t = t0 + tr * 8 + rr;
#pragma unroll
            for (int cc = 0; cc < 8; cc++) {
                int o = o0 + tc * 8 + cc;
                float v = __expf(2.f * (acc[rr][cc] + Ba2[t * 256 + o]));
                E[((((size_t)b << 10) + t) << 8) + o] = f2b(v);   // [b][t][o]
            }
        }
    } else if (mat == 1) {
#pragma unroll
        for (int rr = 0; rr < 8; rr++) {
            int t = t0 + tr * 8 + rr;
            int t1 = (t + 1) & 1023;
#pragma unroll
            for (int cc = 0; cc < 8; cc++) {
                int o = o0 + tc * 8 + cc;
                outStage[(((size_t)b << 10) + t1) * 256 + o] = acc[rr][cc] + Bo2[o] + Bo3[o] + Bo4[o];
            }
        }
    } else {
#pragma unroll
        for (int rr = 0; rr < 8; rr++) {
            int t = t0 + tr * 8 + rr;
#pragma unroll
            for (int cc = 0; cc < 8; cc++)
                ic[(((size_t)b << 10) + t) * 256 + o0 + tc * 8 + cc] = f2b(acc[rr][cc]);
        }
    }
}

// ---------------- K2: scan, 8 blocks/b x 512 thr, flag exchange/step --------
__global__ __launch_bounds__(NTH) void seq8(
    const float* __restrict__ Wa, const float* __restrict__ Va,
    const float* __restrict__ Ba1, const float* __restrict__ Ba3,
    const u16* __restrict__ E, const u16* __restrict__ IC,
    float* __restrict__ out) {
    __shared__ uint32 smWa2[128 * 256];     // 128 KB bf16-packed Wa
    __shared__ __align__(16) float smScratch[2048];
    __shared__ float smPred[256], smQ[256], smF[256], smVa[256], smBa1[256];
    __shared__ float smEe[128], smBa3[128];
    __shared__ float smT[24];

    int tid = threadIdx.x;
    int b = blockIdx.x & 31, g = blockIdx.x >> 5;
    int lane = tid & 63, w = tid >> 6;
    int t0 = g << 7;

    if (tid < 256) {
        smVa[tid] = Va[tid]; smBa1[tid] = Ba1[tid];
        smPred[tid] = 0.f; smQ[tid] = 0.f;
    }
    if (tid < 128) smBa3[tid] = Ba3[t0 + tid];
    for (int idx = tid; idx < 32768; idx += NTH) {
        int j2 = idx >> 8, o = idx & 255;
        uint32 u0 = (uint32)f2b(Wa[(size_t)(2 * j2) * 256 + o]);
        uint32 u1 = (uint32)f2b(Wa[(size_t)(2 * j2 + 1) * 256 + o]);
        smWa2[idx] = u0 | (u1 << 16);
    }
    __syncthreads();

    float sv = (tid < 256) ? smVa[tid] : 0.f;
#pragma unroll
    for (int off = 32; off; off >>= 1) sv += __shfl_xor(sv, off, 64);
    if (lane == 0) smT[w] = sv;
    __syncthreads();
    float sumVa = smT[0] + smT[1] + smT[2] + smT[3];
    float myEmb = (tid < 256) ? g_embWo[tid] : 0.f;
    float M0 = g_M0;
    __syncthreads();

    const u16* Eb = E + ((size_t)b << 18);
    const u16* ICb = IC + ((size_t)b << 18);
    float* outb = out + ((size_t)b << 18);
    long bud = 1000000000L;   // hang guard (bounded: wrong result, not timeout)

    for (int t = 0; t < 1024; t++) {
        uint32* bufP  = &g_Pf[t & 1][b][g][0];
        uint32* flags = &g_flag[t & 1][b][0];
        // UoHp row read — precedes publish (ordering: read -> our publish ->
        // others' flag-pass -> others' write of this row)
        float uoh = (tid < 256) ? outb[((size_t)t << 8) + tid] : 0.f;

        // ---- phase A partials (tid<256) + WaS GEMV (all 512) ----
        float pv = 0.f;
        if (tid < 256) {
            pv = smPred[tid];
            float m = pv;
#pragma unroll
            for (int off = 32; off; off >>= 1) m = fmaxf(m, __shfl_xor(m, off, 64));
            if (lane == 0) smT[w] = m;
        }
        {
            int o = tid & 255, h = tid >> 8;
            const uint32* wp = &smWa2[(h << 6) * 256 + o];
            const float* qp = &smQ[h << 7];
            float a = 0.f;
#pragma unroll 8
            for (int j2 = 0; j2 < 64; j2++) {
                float2 q2 = *(const float2*)&qp[j2 * 2];
                uint32 p = wp[j2 << 8];
                a = fmaf(lo_bf(p), q2.x, a);
                a = fmaf(hi_bf(p), q2.y, a);
            }
            smScratch[tid] = a;
        }
        __syncthreads();   // S1
        if (tid < 256) {
            float M = fmaxf(fmaxf(smT[0], smT[1]), fmaxf(smT[2], smT[3]));
            float e = __expf(pv - M);
            float s1 = e, s2 = e * myEmb;
#pragma unroll
            for (int off = 32; off; off >>= 1) {
                s1 += __shfl_xor(s1, off, 64);
                s2 += __shfl_xor(s2, off, 64);
            }
            if (lane == 0) { smT[4 + w] = s1; smT[8 + w] = s2; }
            smF[tid] = __expf(2.f * (smBa1[tid] + smScratch[tid] + smScratch[256 + tid]));
        }
        __syncthreads();   // S2
        float p_val = (smT[8] + smT[9] + smT[10] + smT[11]) *
                      __builtin_amdgcn_rcpf(smT[4] + smT[5] + smT[6] + smT[7]);

        // ---- phase C: scores + fixed-M0 e + S_g partials, 4 thr/row ----
        // k staggered by oq (R8 PMC: LDS conflicts 8.05e8 -> 0)
        {
            int tl = tid >> 2, oq = tid & 3;
            const uint4* row = (const uint4*)(Eb + (((size_t)(t0 + tl)) << 8) + (oq << 6));
            float acc = 0.f;
#pragma unroll
            for (int k = 0; k < 8; k++) {
                int kk = (k + oq) & 7;
                uint4 ev = row[kk];
                int ob = (oq << 6) + (kk << 3);
                float4 fA = *(const float4*)&smF[ob];
                float4 fB = *(const float4*)&smF[ob + 4];
                float4 vA = *(const float4*)&smVa[ob];
                float4 vB = *(const float4*)&smVa[ob + 4];
                acc = fmaf(vA.x, __builtin_amdgcn_rcpf(fmaf(lo_bf(ev.x), fA.x, 1.f)), acc);
                acc = fmaf(vA.y, __builtin_amdgcn_rcpf(fmaf(hi_bf(ev.x), fA.y, 1.f)), acc);
                acc = fmaf(vA.z, __builtin_amdgcn_rcpf(fmaf(lo_bf(ev.y), fA.z, 1.f)), acc);
                acc = fmaf(vA.w, __builtin_amdgcn_rcpf(fmaf(hi_bf(ev.y), fA.w, 1.f)), acc);
                acc = fmaf(vB.x, __builtin_amdgcn_rcpf(fmaf(lo_bf(ev.z), fB.x, 1.f)), acc);
                acc = fmaf(vB.y, __builtin_amdgcn_rcpf(fmaf(hi_bf(ev.z), fB.y, 1.f)), acc);
                acc = fmaf(vB.z, __builtin_amdgcn_rcpf(fmaf(lo_bf(ev.w), fB.z, 1.f)), acc);
                acc = fmaf(vB.w, __builtin_amdgcn_rcpf(fmaf(hi_bf(ev.w), fB.w, 1.f)), acc);
            }
            // xor-butterfly over bits 0,1 -> ALL 4 quad lanes hold the row sum
            acc += __shfl_xor(acc, 1, 64);
            acc += __shfl_xor(acc, 2, 64);
            float score = sumVa - 2.f * acc + smBa3[tl];
            float e = __expf(score - M0);           // in (0,1], f32-normal
            if (oq == 0) smEe[tl] = e;
            float ls = (oq == 0) ? e : 0.f;         // count each row once
#pragma unroll
            for (int off = 32; off; off >>= 1) ls += __shfl_xor(ls, off, 64);
            if (lane == 0) smT[16 + w] = ls;        // per-wave S_g partial
        }
        __syncthreads();   // S3 — smEe + S_g partials ready

        // ---- P_g partial: e-weighted IC rows of own slice ----
        {
            int rg = tid >> 6, oc = tid & 63, o4 = oc << 2;
            const u16* icp = ICb + (((size_t)t0) << 8) + o4;
            float4 a4 = {0.f, 0.f, 0.f, 0.f};
#pragma unroll 4
            for (int r = 0; r < 16; r++) {
                int row = (rg << 4) + r;
                float e = smEe[row];
                uint2 iv = *(const uint2*)(icp + ((size_t)row << 8));
                a4.x = fmaf(e, lo_bf(iv.x), a4.x);
                a4.y = fmaf(e, hi_bf(iv.x), a4.y);
                a4.z = fmaf(e, lo_bf(iv.y), a4.z);
                a4.w = fmaf(e, hi_bf(iv.y), a4.w);
            }
            *(float4*)&smScratch[rg * 256 + o4] = a4;
        }
        __syncthreads();   // S6
        // ---- publish P (256 f32 words) + S_g at word 256 ----
        if (tid < 256) {
            float Pmine = 0.f;
#pragma unroll
            for (int rg = 0; rg < 8; rg++) Pmine += smScratch[rg * 256 + tid];
            coh_st(&bufP[tid], __float_as_uint(Pmine));
        }
        if (tid == 0) {
            float S_g = smT[16] + smT[17] + smT[18] + smT[19] +
                        smT[20] + smT[21] + smT[22] + smT[23];
            coh_st(&bufP[256], __float_as_uint(S_g));
        }
        __syncthreads();   // S7 — vmcnt(0) drain = release fence for publishes
        // ---- flag store + poll 7 foreign flags ----
        if (tid == 0) coh_st(&flags[g], (uint32)t);
        if (tid < 8 && tid != g) {
            while (bud > 0) {
                if (atomicAdd(&flags[tid], 0u) == (uint32)t) break;
                bud--;
            }
        }
        __syncthreads();   // S8 — all 8 groups' data globally visible
        // ---- merge: pure sums (no max, no exp) ----
        if (tid < 256) {
            const uint32* pb = &g_Pf[t & 1][b][0][0];
            float Pt = 0.f;
#pragma unroll
            for (int g2 = 0; g2 < 8; g2++)
                Pt += __uint_as_float(coh_ld(&pb[g2 * 264 + tid]));
            uint32 sown = 0;
            if (lane < 8) sown = coh_ld(&pb[lane * 264 + 256]);
            float L = 0.f;
#pragma unroll
            for (int g2 = 0; g2 < 8; g2++)
                L += __uint_as_float(__shfl(sown, g2, 64));
            float pr = p_val + uoh + Pt * __builtin_amdgcn_rcpf(L);
            if ((tid >> 5) == g) outb[((size_t)t << 8) + tid] = pr;
            smPred[tid] = pr;
            smQ[tid] = tanh_fast(pr);
        }
        __syncthreads();   // S9
    }
}

// ---------------- fallback (ws too small): diagnostic zero-fill ----------------
__global__ void zero_k(uint32* out, int n) {
    int i = blockIdx.x * 1024 + threadIdx.x;
    if (i < n) out[i] = 0;
}

extern "C" void kernel_launch(void* const* d_in, const int* in_sizes, int n_in,
                              void* d_out, int out_size, void* d_ws, size_t ws_size,
                              hipStream_t stream) {
    const float* in = (const float*)d_in[0];
    const float* Wa = (const float*)d_in[1];
    const float* Ua = (const float*)d_in[2];
    const float* Va = (const float*)d_in[3];
    const float* Ba1 = (const float*)d_in[4];
    const float* Ba2 = (const float*)d_in[5];
    const float* Ba3 = (const float*)d_in[6];
    const float* Wo = (const float*)d_in[7];
    const float* Uo = (const float*)d_in[8];
    const float* Co = (const float*)d_in[9];
    const float* Bo2 = (const float*)d_in[10];
    const float* Bo3 = (const float*)d_in[11];
    const float* Bo4 = (const float*)d_in[12];
    const float* emb = (const float*)d_in[13];
    float* out = (float*)d_out;
    char* ws = (char*)d_ws;

    if (ws_size < WS_NEEDED) {
        zero_k<<<(out_size + 1023) / 1024, 1024, 0, stream>>>((uint32*)out, out_size);
        return;
    }

    u16* E = (u16*)(ws + OFF_E);
    u16* icp = (u16*)(ws + OFF_IC);

    init_flags<<<1, 512, 0, stream>>>();
    setup_misc<<<1, 256, 0, stream>>>(emb, Wo, Va, Ba3);
    gemm_pre<<<dim3(256, 6), 256, 0, stream>>>(in, Ua, Uo, Co, Ba2, Bo2, Bo3, Bo4, E, out, icp);
    seq8<<<256, NTH, 0, stream>>>(Wa, Va, Ba1, Ba3, E, icp, out);
}